// Round 15
// baseline (304.267 us; speedup 1.0000x reference)
//
#include <hip/hip_runtime.h>
#include <hip/hip_bf16.h>

#define PD 272            // padded expm dim (257 -> 272)
#define PD2 (PD*PD)       // 73984
#define D 256
#define BATCH 262144
#define NT (BATCH/16)     // 16384 16-row tiles
#define G 768             // gemm grid: 3 blocks/CU (48KB LDS each)

typedef __bf16 bf16x8 __attribute__((ext_vector_type(8)));
typedef float  f32x4  __attribute__((ext_vector_type(4)));

#define WAITV(n) asm volatile("s_waitcnt vmcnt(" #n ")" ::: "memory")

// ================= expm chain (fp32, 272-padded, 3 kernels) ==============
// ||M*dt|| ~ 1.6 -> degree-8 Paterson-Stockmeyer Taylor, remainder ~2e-4
// << bf16 rounding of Phi. E = (c0I+c1M+c2M2+c3M3) + M4*W,
// W = c4I+c5M+c6M2+c7M3+c8M4, M4 = M2^2.

__device__ __forceinline__ float dotPD(const float* __restrict__ xr,
                                       const float* __restrict__ yc) {
    float a[16];
    #pragma unroll
    for (int u = 0; u < 16; ++u) a[u] = 0.f;
    #pragma unroll 2
    for (int k0 = 0; k0 < PD; k0 += 16) {
        #pragma unroll
        for (int u = 0; u < 16; ++u)
            a[u] = fmaf(xr[k0 + u], yc[(size_t)(k0 + u) * PD], a[u]);
    }
    float s = 0.f;
    #pragma unroll
    for (int u = 0; u < 16; ++u) s += a[u];
    return s;
}

// e1: Ms = M*dt (on the fly); M2 = Ms^2
__global__ void expm_mm1(const float* __restrict__ A, const float* __restrict__ b,
                         const int* __restrict__ t0, const int* __restrict__ tf,
                         float* __restrict__ Ms, float* __restrict__ M2) {
    int idx = blockIdx.x * blockDim.x + threadIdx.x;
    if (idx >= PD2) return;
    int i = idx / PD, j = idx - i * PD;
    float sc = (float)(tf[0] - t0[0]);
    float mv = 0.f;
    if (i < D && j < D) mv = A[i * D + j] * sc;
    else if (i < D && j == D) mv = b[i] * sc;
    Ms[idx] = mv;
    float acc = 0.f;
    if (i < D && j <= D) {
        const float* xr = A + (size_t)i * D;
        float a[16];
        #pragma unroll
        for (int u = 0; u < 16; ++u) a[u] = 0.f;
        if (j < D) {
            const float* yc = A + j;
            #pragma unroll 2
            for (int k0 = 0; k0 < D; k0 += 16) {
                #pragma unroll
                for (int u = 0; u < 16; ++u)
                    a[u] = fmaf(xr[k0 + u], yc[(size_t)(k0 + u) * D], a[u]);
            }
        } else {
            for (int k0 = 0; k0 < D; k0 += 16) {
                #pragma unroll
                for (int u = 0; u < 16; ++u)
                    a[u] = fmaf(xr[k0 + u], b[k0 + u], a[u]);
            }
        }
        float s = 0.f;
        #pragma unroll
        for (int u = 0; u < 16; ++u) s += a[u];
        acc = s * sc * sc;
    }
    M2[idx] = acc;
}

// e2: dual-dot off one shared M2-row stream:
//   M3 = M2*Ms, M4 = M2*M2, W = c4I+c5Ms+c6M2+c7M3+c8M4
__global__ void expm_mm2(const float* __restrict__ Ms, const float* __restrict__ M2,
                         float* __restrict__ M3, float* __restrict__ M4,
                         float* __restrict__ W) {
    int idx = blockIdx.x * blockDim.x + threadIdx.x;
    if (idx >= PD2) return;
    int i = idx / PD, j = idx - i * PD;
    const float* xr = M2 + (size_t)i * PD;
    const float* y3 = Ms + j;
    const float* y4 = M2 + j;
    float a3[8], a4[8];
    #pragma unroll
    for (int u = 0; u < 8; ++u) { a3[u] = 0.f; a4[u] = 0.f; }
    #pragma unroll 2
    for (int k0 = 0; k0 < PD; k0 += 8) {
        #pragma unroll
        for (int u = 0; u < 8; ++u) {
            float xv = xr[k0 + u];
            a3[u] = fmaf(xv, y3[(size_t)(k0 + u) * PD], a3[u]);
            a4[u] = fmaf(xv, y4[(size_t)(k0 + u) * PD], a4[u]);
        }
    }
    float v3 = ((a3[0]+a3[1])+(a3[2]+a3[3])) + ((a3[4]+a3[5])+(a3[6]+a3[7]));
    float v4 = ((a4[0]+a4[1])+(a4[2]+a4[3])) + ((a4[4]+a4[5])+(a4[6]+a4[7]));
    M3[idx] = v3;
    M4[idx] = v4;
    const float c4 = 1.f/24.f, c5 = 1.f/120.f, c6 = 1.f/720.f,
                c7 = 1.f/5040.f, c8 = 1.f/40320.f;
    float w = (i == j) ? c4 : 0.f;
    w = fmaf(c5, Ms[idx], w);
    w = fmaf(c6, M2[idx], w);
    w = fmaf(c7, v3, w);
    w = fmaf(c8, v4, w);
    W[idx] = w;
}

// e3: E = c0I+c1Ms+c2M2+c3M3 + M4*W; emit PhiB (bf16 [n][k]) + aff directly
__global__ void expm_mm3(const float* __restrict__ M4, const float* __restrict__ W,
                         const float* __restrict__ Ms, const float* __restrict__ M2,
                         const float* __restrict__ M3,
                         __bf16* __restrict__ PhiB, float* __restrict__ aff) {
    int idx = blockIdx.x * blockDim.x + threadIdx.x;
    if (idx >= PD2) return;
    int i = idx / PD, j = idx - i * PD;
    if (i >= D || j > D) return;
    float v = dotPD(M4 + (size_t)i * PD, W + j);
    float e = (i == j) ? 1.f : 0.f;
    e += Ms[idx];
    e = fmaf(0.5f, M2[idx], e);
    e = fmaf(1.f/6.f, M3[idx], e);
    e += v;
    if (j < D) PhiB[i * D + j] = (__bf16)e;
    else       aff[i] = e;
}

// ================= main GEMM =============================================
// out[m][n] = sum_k X[m][k]*Phi[n][k] + aff[n]
// R13 champion (128.4us) + OCCUPANCY 16->24 waves/CU in the NEW structure:
// ring 3->2 (depth-1 prefetch; R10: depth irrelevant, step 3.2us >> 900cyc
// latency) cuts LDS to 48KB -> 3 blocks/CU; G=768 (256 blocks do 22 tiles,
// 512 do 21); launch_bounds(512,6) (VGPR cap 85 >= measured 64).
// Per-step: WAITV; BAR A; stage(i+1); compute->outb (swizzled, conflict-
// free); lgkm0; BAR B; flush = 1KB-contiguous NT stores (R13's win).
// Wait ladder (ring-2): step0 vmcnt(0); steady vmcnt(2)
// (queue = [stage(i):2][NTst(i-1):2]).
__global__ __launch_bounds__(512, 6) void gemm_out(
    const float* __restrict__ X, const __bf16* __restrict__ PhiB,
    const float* __restrict__ aff, float* __restrict__ out) {
    __shared__ float ring[2][4096];      // 2 x 16 KB in-tile double buffer
    __shared__ float outb[4096];         // 16 KB out-stage

    const int lane = threadIdx.x & 63;
    const int wid  = threadIdx.x >> 6;   // 0..7
    const int col  = lane & 15;          // X row within tile = D-col (m)
    const int g    = lane >> 4;          // k-group
    const int n0   = wid * 32;
    const int bid  = blockIdx.x;
    const int xr   = (col & 7) << 4;

    // tiles for this block: bid, bid+G, ... (22 tiles for bid<256, else 21)
    const int myNT = (NT - bid + G - 1) / G;

    // ---- Phi fragments: 2 n-tiles x 8 ks, pinned in registers ----
    f32x4 bfr[2][8];
    #pragma unroll
    for (int t4 = 0; t4 < 2; ++t4) {
        const char* bp = (const char*)PhiB + (size_t)2 * ((n0 + t4 * 16 + col) * D + g * 8);
        #pragma unroll
        for (int ks = 0; ks < 8; ++ks)
            bfr[t4][ks] = *(const f32x4*)(bp + 2 * ks * 32);
    }
    #pragma unroll
    for (int t4 = 0; t4 < 2; ++t4)
        #pragma unroll
        for (int ks = 0; ks < 8; ++ks)
            asm volatile("" : "+v"(bfr[t4][ks]));

    f32x4 avv[2];
    #pragma unroll
    for (int t4 = 0; t4 < 2; ++t4)
        avv[t4] = *(const f32x4*)(aff + n0 + t4 * 16 + 4 * g);
    #pragma unroll
    for (int t4 = 0; t4 < 2; ++t4) asm volatile("" : "+v"(avv[t4]));

    // stage tile i (tile id = bid + i*G) into ring buf i&1 (1KB/row, contig)
    auto stage = [&](int i) __attribute__((always_inline)) {
        const char* src = (const char*)(X + (size_t)(bid + (size_t)i * G) * 4096);
        #pragma unroll
        for (int q = 0; q < 2; ++q) {
            int row = wid * 2 + q;
            const char* gp = src + row * 1024 + ((lane * 16) ^ ((row & 7) << 4));
            __builtin_amdgcn_global_load_lds(gp, &ring[i & 1][row * 256], 16, 0, 0);
        }
    };

    // MFMA for tile i's buffer; write result into outb (swizzled)
    auto compute = [&](int i) __attribute__((always_inline)) {
        const char* lb = (const char*)&ring[i & 1][0] + col * 1024;
        f32x4 acc0 = (f32x4){0.f, 0.f, 0.f, 0.f};
        f32x4 acc1 = (f32x4){0.f, 0.f, 0.f, 0.f};
        #pragma unroll
        for (int ks = 0; ks < 8; ++ks) {
            int c = 32 * g + 128 * ks;
            f32x4 lo = *(const f32x4*)(lb + (c ^ xr));
            f32x4 hi = *(const f32x4*)(lb + ((c + 16) ^ xr));
            bf16x8 a;
            #pragma unroll
            for (int j = 0; j < 4; ++j) {
                a[j]     = (__bf16)lo[j];
                a[4 + j] = (__bf16)hi[j];
            }
            acc0 = __builtin_amdgcn_mfma_f32_16x16x32_bf16(
                __builtin_bit_cast(bf16x8, bfr[0][ks]), a, acc0, 0, 0, 0);
            acc1 = __builtin_amdgcn_mfma_f32_16x16x32_bf16(
                __builtin_bit_cast(bf16x8, bfr[1][ks]), a, acc1, 0, 0, 0);
        }
        // outb[row=col][byte: wid*128 + t4*64 + g*16], XOR (col&7)<<4.
        char* ob = (char*)outb + col * 1024;
        *(f32x4*)(ob + ((wid * 128 + g * 16) ^ xr))      = acc0 + avv[0];
        *(f32x4*)(ob + ((wid * 128 + 64 + g * 16) ^ xr)) = acc1 + avv[1];
    };

    // read back 2 full rows, store 1KB-contiguous NON-TEMPORAL
    auto flush = [&](int i) __attribute__((always_inline)) {
        #pragma unroll
        for (int q = 0; q < 2; ++q) {
            int row = wid * 2 + q;
            f32x4 v = *(const f32x4*)((const char*)outb + row * 1024
                                      + ((lane * 16) ^ ((row & 7) << 4)));
            float* dst = out + ((size_t)(bid + (size_t)i * G) * 16 + row) * D + lane * 4;
            __builtin_nontemporal_store(v, (f32x4*)dst);
        }
    };

    #define BAR()                                   \
        __builtin_amdgcn_sched_barrier(0);          \
        __builtin_amdgcn_s_barrier();               \
        __builtin_amdgcn_sched_barrier(0)

    stage(0);

    for (int i = 0; i < myNT; ++i) {
        // queue at top of step i: [stage(i):2][NTst(i-1):2] -> stage(i) done
        if (i == 0) { WAITV(0); } else { WAITV(2); }
        BAR();                               // ring[i&1] ready; outb free
        if (i + 1 < myNT) stage(i + 1);
        __builtin_amdgcn_sched_barrier(0);
        compute(i);
        asm volatile("s_waitcnt lgkmcnt(0)" ::: "memory");
        BAR();                               // outb fully written
        flush(i);
    }
    #undef BAR
}

// ================= launch ================================================

extern "C" void kernel_launch(void* const* d_in, const int* in_sizes, int n_in,
                              void* d_out, int out_size, void* d_ws, size_t ws_size,
                              hipStream_t stream) {
    const float* X  = (const float*)d_in[0];
    const float* A  = (const float*)d_in[1];
    const float* b  = (const float*)d_in[2];
    const int*   t0 = (const int*)d_in[3];
    const int*   tf = (const int*)d_in[4];
    float* out = (float*)d_out;

    float* ws = (float*)d_ws;
    float* Ms = ws + 0 * PD2;
    float* M2 = ws + 1 * PD2;
    float* M3 = ws + 2 * PD2;
    float* M4 = ws + 3 * PD2;
    float* W  = ws + 4 * PD2;
    __bf16* PhiB = (__bf16*)(ws + 5 * PD2);
    float*  aff  = ws + 5 * PD2 + (D * D) / 2;

    const int g1 = (PD2 + 255) / 256;

    expm_mm1<<<g1, 256, 0, stream>>>(A, b, t0, tf, Ms, M2);
    expm_mm2<<<g1, 256, 0, stream>>>(Ms, M2, M3, M4, W);
    expm_mm3<<<g1, 256, 0, stream>>>(M4, W, Ms, M2, M3, PhiB, aff);

    gemm_out<<<G, 512, 0, stream>>>(X, PhiB, aff, out);
}

// Round 16
// 114.869 us; speedup vs baseline: 2.6488x; 2.6488x over previous
//
#include <hip/hip_runtime.h>
#include <hip/hip_bf16.h>

#define PD 272            // padded expm dim (257 -> 272)
#define PD2 (PD*PD)       // 73984
#define D 256
#define BATCH 262144
#define NT (BATCH/16)     // 16384 16-row tiles
#define G 512             // gemm grid: 2 blocks/CU, 32 tiles/block
#define NSTEP (NT/G)      // 32
#define EG (PD2/64)       // 1156 expm blocks (64 elements x 4 k-slices each)

typedef __bf16 bf16x8 __attribute__((ext_vector_type(8)));
typedef float  f32x4  __attribute__((ext_vector_type(4)));

#define WAITV(n) asm volatile("s_waitcnt vmcnt(" #n ")" ::: "memory")

// ================= expm chain (fp32, 272-padded, 3 kernels) ==============
// ||M*dt|| ~ 1.6 -> degree-8 Paterson-Stockmeyer Taylor, remainder ~2e-4
// << bf16 rounding of Phi. E = (c0I+c1M+c2M2+c3M3) + M4*W,
// W = c4I+c5M+c6M2+c7M3+c8M4, M4 = M2^2.
// K-SPLIT x4 (R16): each element computed by 4 threads (68-long chains, not
// 272), partials reduced via LDS; grid 289->1156 blocks -> ~18 waves/CU so
// the L2-latency chains overlap. Block: t = s*64+e; element idx =
// blockIdx*64+e; thread handles k in [s*KS, (s+1)*KS).

// e1: Ms = M*dt; M2 = Ms^2 (dot over k<D, k-split 4x64)
__global__ __launch_bounds__(256) void expm_mm1(
    const float* __restrict__ A, const float* __restrict__ b,
    const int* __restrict__ t0, const int* __restrict__ tf,
    float* __restrict__ Ms, float* __restrict__ M2) {
    __shared__ float p[4][64];
    const int t = threadIdx.x, s = t >> 6, e = t & 63;
    const int idx = blockIdx.x * 64 + e;
    const int i = idx / PD, j = idx - i * PD;
    const float sc = (float)(tf[0] - t0[0]);

    float part = 0.f;
    if (i < D && j <= D) {
        const float* xr = A + (size_t)i * D + s * 64;
        float a[4] = {0.f, 0.f, 0.f, 0.f};
        if (j < D) {
            const float* yc = A + j + (size_t)(s * 64) * D;
            #pragma unroll 4
            for (int k = 0; k < 64; k += 4) {
                #pragma unroll
                for (int u = 0; u < 4; ++u)
                    a[u] = fmaf(xr[k + u], yc[(size_t)(k + u) * D], a[u]);
            }
        } else {
            const float* bc = b + s * 64;
            #pragma unroll 4
            for (int k = 0; k < 64; k += 4) {
                #pragma unroll
                for (int u = 0; u < 4; ++u)
                    a[u] = fmaf(xr[k + u], bc[k + u], a[u]);
            }
        }
        part = (a[0] + a[1]) + (a[2] + a[3]);
    }
    p[s][e] = part;
    __syncthreads();
    if (s == 0) {
        float mv = 0.f;
        if (i < D && j < D) mv = A[i * D + j] * sc;
        else if (i < D && j == D) mv = b[i] * sc;
        Ms[idx] = mv;
        M2[idx] = (p[0][e] + p[1][e] + p[2][e] + p[3][e]) * sc * sc;
    }
}

// e2: M3 = M2*Ms, M4 = M2*M2 (dual dot over PD, k-split 4x68);
//     W = c4I+c5Ms+c6M2+c7M3+c8M4
__global__ __launch_bounds__(256) void expm_mm2(
    const float* __restrict__ Ms, const float* __restrict__ M2,
    float* __restrict__ M3, float* __restrict__ M4, float* __restrict__ W) {
    __shared__ float p3[4][64], p4[4][64];
    const int t = threadIdx.x, s = t >> 6, e = t & 63;
    const int idx = blockIdx.x * 64 + e;
    const int i = idx / PD, j = idx - i * PD;

    const float* xr = M2 + (size_t)i * PD + s * 68;
    const float* y3 = Ms + j + (size_t)(s * 68) * PD;
    const float* y4 = M2 + j + (size_t)(s * 68) * PD;
    float a3[4] = {0.f, 0.f, 0.f, 0.f};
    float a4[4] = {0.f, 0.f, 0.f, 0.f};
    #pragma unroll 4
    for (int k = 0; k < 68; k += 4) {
        #pragma unroll
        for (int u = 0; u < 4; ++u) {
            float xv = xr[k + u];
            a3[u] = fmaf(xv, y3[(size_t)(k + u) * PD], a3[u]);
            a4[u] = fmaf(xv, y4[(size_t)(k + u) * PD], a4[u]);
        }
    }
    p3[s][e] = (a3[0] + a3[1]) + (a3[2] + a3[3]);
    p4[s][e] = (a4[0] + a4[1]) + (a4[2] + a4[3]);
    __syncthreads();
    if (s == 0) {
        float v3 = p3[0][e] + p3[1][e] + p3[2][e] + p3[3][e];
        float v4 = p4[0][e] + p4[1][e] + p4[2][e] + p4[3][e];
        M3[idx] = v3;
        M4[idx] = v4;
        const float c4 = 1.f/24.f, c5 = 1.f/120.f, c6 = 1.f/720.f,
                    c7 = 1.f/5040.f, c8 = 1.f/40320.f;
        float w = (i == j) ? c4 : 0.f;
        w = fmaf(c5, Ms[idx], w);
        w = fmaf(c6, M2[idx], w);
        w = fmaf(c7, v3, w);
        w = fmaf(c8, v4, w);
        W[idx] = w;
    }
}

// e3: E = c0I+c1Ms+c2M2+c3M3 + M4*W (dot k-split 4x68); emit PhiB + aff
__global__ __launch_bounds__(256) void expm_mm3(
    const float* __restrict__ M4, const float* __restrict__ W,
    const float* __restrict__ Ms, const float* __restrict__ M2,
    const float* __restrict__ M3,
    __bf16* __restrict__ PhiB, float* __restrict__ aff) {
    __shared__ float p[4][64];
    const int t = threadIdx.x, s = t >> 6, e = t & 63;
    const int idx = blockIdx.x * 64 + e;
    const int i = idx / PD, j = idx - i * PD;

    const float* xr = M4 + (size_t)i * PD + s * 68;
    const float* yc = W + j + (size_t)(s * 68) * PD;
    float a[4] = {0.f, 0.f, 0.f, 0.f};
    #pragma unroll 4
    for (int k = 0; k < 68; k += 4) {
        #pragma unroll
        for (int u = 0; u < 4; ++u)
            a[u] = fmaf(xr[k + u], yc[(size_t)(k + u) * PD], a[u]);
    }
    p[s][e] = (a[0] + a[1]) + (a[2] + a[3]);
    __syncthreads();
    if (s == 0 && i < D && j <= D) {
        float v = p[0][e] + p[1][e] + p[2][e] + p[3][e];
        float ev = (i == j) ? 1.f : 0.f;
        ev += Ms[idx];
        ev = fmaf(0.5f, M2[idx], ev);
        ev = fmaf(1.f/6.f, M3[idx], ev);
        ev += v;
        if (j < D) PhiB[i * D + j] = (__bf16)ev;
        else       aff[i] = ev;
    }
}

// ================= main GEMM (EXACT R13 champion, 128.4us) ===============
// out[m][n] = sum_k X[m][k]*Phi[n][k] + aff[n]
// 8 waves, n-split 32 cols/wave, Phi frags pinned; X in 3x16KB ring via
// global_load_lds w=16 (XOR-preswizzled source), depth-2 prefetch;
// acc -> outb (XOR-swizzled, conflict-free) -> 1KB-contiguous NT stores.
__global__ __launch_bounds__(512, 4) void gemm_out(
    const float* __restrict__ X, const __bf16* __restrict__ PhiB,
    const float* __restrict__ aff, float* __restrict__ out) {
    __shared__ float ring[3][4096];      // 3 x 16 KB in-tile ring
    __shared__ float outb[4096];         // 16 KB out-stage

    const int lane = threadIdx.x & 63;
    const int wid  = threadIdx.x >> 6;   // 0..7
    const int col  = lane & 15;          // X row within tile = D-col (m)
    const int g    = lane >> 4;          // k-group
    const int n0   = wid * 32;
    const int bid  = blockIdx.x;
    const int xr   = (col & 7) << 4;

    // ---- Phi fragments: 2 n-tiles x 8 ks, pinned in registers ----
    f32x4 bfr[2][8];
    #pragma unroll
    for (int t4 = 0; t4 < 2; ++t4) {
        const char* bp = (const char*)PhiB + (size_t)2 * ((n0 + t4 * 16 + col) * D + g * 8);
        #pragma unroll
        for (int ks = 0; ks < 8; ++ks)
            bfr[t4][ks] = *(const f32x4*)(bp + 2 * ks * 32);
    }
    #pragma unroll
    for (int t4 = 0; t4 < 2; ++t4)
        #pragma unroll
        for (int ks = 0; ks < 8; ++ks)
            asm volatile("" : "+v"(bfr[t4][ks]));

    f32x4 avv[2];
    #pragma unroll
    for (int t4 = 0; t4 < 2; ++t4)
        avv[t4] = *(const f32x4*)(aff + n0 + t4 * 16 + 4 * g);
    #pragma unroll
    for (int t4 = 0; t4 < 2; ++t4) asm volatile("" : "+v"(avv[t4]));

    // stage tile i (tile id = bid + i*G) into ring buf i%3 (1KB/row, contig)
    auto stage = [&](int i) __attribute__((always_inline)) {
        const char* src = (const char*)(X + (size_t)(bid + (size_t)i * G) * 4096);
        #pragma unroll
        for (int q = 0; q < 2; ++q) {
            int row = wid * 2 + q;
            const char* gp = src + row * 1024 + ((lane * 16) ^ ((row & 7) << 4));
            __builtin_amdgcn_global_load_lds(gp, &ring[i % 3][row * 256], 16, 0, 0);
        }
    };

    // MFMA for tile i's buffer; write result into outb (swizzled)
    auto compute = [&](int i) __attribute__((always_inline)) {
        const char* lb = (const char*)&ring[i % 3][0] + col * 1024;
        f32x4 acc0 = (f32x4){0.f, 0.f, 0.f, 0.f};
        f32x4 acc1 = (f32x4){0.f, 0.f, 0.f, 0.f};
        #pragma unroll
        for (int ks = 0; ks < 8; ++ks) {
            int c = 32 * g + 128 * ks;
            f32x4 lo = *(const f32x4*)(lb + (c ^ xr));
            f32x4 hi = *(const f32x4*)(lb + ((c + 16) ^ xr));
            bf16x8 a;
            #pragma unroll
            for (int j = 0; j < 4; ++j) {
                a[j]     = (__bf16)lo[j];
                a[4 + j] = (__bf16)hi[j];
            }
            acc0 = __builtin_amdgcn_mfma_f32_16x16x32_bf16(
                __builtin_bit_cast(bf16x8, bfr[0][ks]), a, acc0, 0, 0, 0);
            acc1 = __builtin_amdgcn_mfma_f32_16x16x32_bf16(
                __builtin_bit_cast(bf16x8, bfr[1][ks]), a, acc1, 0, 0, 0);
        }
        // outb[row=col][byte: wid*128 + t4*64 + g*16], XOR (col&7)<<4.
        char* ob = (char*)outb + col * 1024;
        *(f32x4*)(ob + ((wid * 128 + g * 16) ^ xr))      = acc0 + avv[0];
        *(f32x4*)(ob + ((wid * 128 + 64 + g * 16) ^ xr)) = acc1 + avv[1];
    };

    // read back 2 full rows, store 1KB-contiguous NON-TEMPORAL
    auto flush = [&](int i) __attribute__((always_inline)) {
        #pragma unroll
        for (int q = 0; q < 2; ++q) {
            int row = wid * 2 + q;
            f32x4 v = *(const f32x4*)((const char*)outb + row * 1024
                                      + ((lane * 16) ^ ((row & 7) << 4)));
            float* dst = out + ((size_t)(bid + (size_t)i * G) * 16 + row) * D + lane * 4;
            __builtin_nontemporal_store(v, (f32x4*)dst);
        }
    };

    #define BAR()                                   \
        __builtin_amdgcn_sched_barrier(0);          \
        __builtin_amdgcn_s_barrier();               \
        __builtin_amdgcn_sched_barrier(0)

    stage(0); stage(1);

    for (int i = 0; i < NSTEP; ++i) {
        // wait: stage(i) complete (exact in-order queue, as in R11/R13)
        if (i == 0)            { WAITV(2); }
        else if (i == 1)       { WAITV(4); }
        else if (i < NSTEP-1)  { WAITV(6); }
        else                   { WAITV(4); }
        BAR();                               // ring[i%3] ready; outb free
        if (i + 2 < NSTEP) stage(i + 2);
        __builtin_amdgcn_sched_barrier(0);
        compute(i);
        asm volatile("s_waitcnt lgkmcnt(0)" ::: "memory");
        BAR();                               // outb fully written
        flush(i);
    }
    #undef BAR
}

// ================= launch ================================================

extern "C" void kernel_launch(void* const* d_in, const int* in_sizes, int n_in,
                              void* d_out, int out_size, void* d_ws, size_t ws_size,
                              hipStream_t stream) {
    const float* X  = (const float*)d_in[0];
    const float* A  = (const float*)d_in[1];
    const float* b  = (const float*)d_in[2];
    const int*   t0 = (const int*)d_in[3];
    const int*   tf = (const int*)d_in[4];
    float* out = (float*)d_out;

    float* ws = (float*)d_ws;
    float* Ms = ws + 0 * PD2;
    float* M2 = ws + 1 * PD2;
    float* M3 = ws + 2 * PD2;
    float* M4 = ws + 3 * PD2;
    float* W  = ws + 4 * PD2;
    __bf16* PhiB = (__bf16*)(ws + 5 * PD2);
    float*  aff  = ws + 5 * PD2 + (D * D) / 2;

    expm_mm1<<<EG, 256, 0, stream>>>(A, b, t0, tf, Ms, M2);
    expm_mm2<<<EG, 256, 0, stream>>>(Ms, M2, M3, M4, W);
    expm_mm3<<<EG, 256, 0, stream>>>(M4, W, Ms, M2, M3, PhiB, aff);

    gemm_out<<<G, 512, 0, stream>>>(X, PhiB, aff, out);
}